// Round 1
// baseline (2093.912 us; speedup 1.0000x reference)
//
#include <hip/hip_runtime.h>
#include <math.h>

#define ND 128
#define ED 64
#define LN_EPS 1e-5f
#define TE 64   // edges per block (edge kernel)
#define TN 64   // nodes per block (gru kernel)

__device__ __forceinline__ float sigmoidf_(float x) {
    return 1.f / (1.f + expf(-x));
}

// ---------------- edge message kernel ----------------
// block: 256 threads = 4 waves. lane (tid&63) = edge slot within 64-edge tile.
// wave w handles output columns [32w, 32w+32). Weight addresses wave-uniform
// (readfirstlane) -> scalar loads; LDS x reads lane-strided, conflict-free.
__global__ __launch_bounds__(256, 2)
void edge_kernel(const float* __restrict__ nf,
                 const int* __restrict__ eidx,
                 const float* __restrict__ ef,
                 const float* __restrict__ W1, const float* __restrict__ b1,
                 const float* __restrict__ ln_g, const float* __restrict__ ln_b,
                 const float* __restrict__ W2, const float* __restrict__ b2,
                 const float* __restrict__ gate_w, const float* __restrict__ gate_b,
                 float* __restrict__ agg, int E)
{
    __shared__ float sx[TE][65];      // current 64-wide k-chunk of edge inputs
    __shared__ float sp[TE][129];     // LN+ReLU activations, then messages
    __shared__ float sred[4][TE][2];  // per-wave LayerNorm partials
    __shared__ int ssrc[TE];
    __shared__ int sdst[TE];

    const int tid  = threadIdx.x;
    const int lane = tid & 63;                                   // edge slot
    const int w    = __builtin_amdgcn_readfirstlane(tid >> 6);   // wave id 0..3
    const int cb   = w * 32;                                     // column base
    const int e0   = blockIdx.x * TE;

    if (tid < TE)            ssrc[tid]      = eidx[e0 + tid];
    else if (tid < 2 * TE)   sdst[tid - TE] = eidx[E + e0 + (tid - TE)];
    __syncthreads();

    float acc[32];
    #pragma unroll
    for (int j = 0; j < 32; ++j) acc[j] = 0.f;
    float gate = 0.f;

    const int r = tid >> 2, q = tid & 3;   // staging: 4 threads per row
    for (int kc = 0; kc < 5; ++kc) {
        // ---- stage chunk kc: 64 rows x 64 floats ----
        const float* base;
        if (kc < 2)      base = nf + (size_t)ssrc[r] * ND + (kc & 1) * 64;
        else if (kc < 4) base = nf + (size_t)sdst[r] * ND + (kc & 1) * 64;
        else             base = ef + (size_t)(e0 + r) * ED;
        #pragma unroll
        for (int i = 0; i < 4; ++i) {
            int f4 = q + 4 * i;            // 16 float4 per row / 4 threads
            float4 v = *(const float4*)(base + f4 * 4);
            sx[r][f4*4+0] = v.x; sx[r][f4*4+1] = v.y;
            sx[r][f4*4+2] = v.z; sx[r][f4*4+3] = v.w;
        }
        __syncthreads();
        // ---- accumulate matmul1 over this chunk ----
        const float* Wc = W1 + (size_t)(kc * 64) * ND + cb;
        for (int kk = 0; kk < 64; ++kk) {
            float x = sx[lane][kk];
            const float* wr = Wc + (size_t)kk * ND;
            #pragma unroll
            for (int j = 0; j < 32; ++j) acc[j] = fmaf(x, wr[j], acc[j]);
        }
        if (kc == 4) {
            // sigmoid gate from raw edge features (currently staged in sx)
            float g = 0.f;
            for (int kk = 0; kk < 64; ++kk) g = fmaf(sx[lane][kk], gate_w[kk], g);
            gate = sigmoidf_(g + gate_b[0]);
        }
        __syncthreads();   // everyone done with sx before restage
    }

    // ---- bias + LayerNorm ----
    float s1 = 0.f, s2 = 0.f;
    #pragma unroll
    for (int j = 0; j < 32; ++j) {
        acc[j] += b1[cb + j];
        s1 += acc[j];
        s2 += acc[j] * acc[j];
    }
    sred[w][lane][0] = s1; sred[w][lane][1] = s2;
    __syncthreads();
    float t1 = 0.f, t2 = 0.f;
    #pragma unroll
    for (int ww = 0; ww < 4; ++ww) { t1 += sred[ww][lane][0]; t2 += sred[ww][lane][1]; }
    const float mu   = t1 * (1.f / 128.f);
    const float var  = t2 * (1.f / 128.f) - mu * mu;
    const float rstd = rsqrtf(var + LN_EPS);
    #pragma unroll
    for (int j = 0; j < 32; ++j) {
        float v = (acc[j] - mu) * rstd * ln_g[cb + j] + ln_b[cb + j];
        sp[lane][cb + j] = v > 0.f ? v : 0.f;   // ReLU
    }
    __syncthreads();

    // ---- matmul2: 128 -> 128 ----
    float acc2[32];
    #pragma unroll
    for (int j = 0; j < 32; ++j) acc2[j] = 0.f;
    for (int k = 0; k < ND; ++k) {
        float x = sp[lane][k];
        const float* wr = W2 + (size_t)k * ND + cb;
        #pragma unroll
        for (int j = 0; j < 32; ++j) acc2[j] = fmaf(x, wr[j], acc2[j]);
    }
    __syncthreads();   // all waves done reading sp
    #pragma unroll
    for (int j = 0; j < 32; ++j)
        sp[lane][cb + j] = (acc2[j] + b2[cb + j]) * gate;
    __syncthreads();

    // ---- scatter-add, transposed for coalesced atomics ----
    const int col  = tid & 127;
    const int half = tid >> 7;   // 0 or 1 -> two rows per iteration
    for (int ee = 0; ee < TE; ee += 2) {
        int e = ee + half;
        atomicAdd(&agg[(size_t)sdst[e] * ND + col], sp[e][col]);
    }
}

// ---------------- GRU update kernel ----------------
// block: 512 threads = 8 waves. lane = node slot (64 nodes/block),
// wave w handles output columns [16w, 16w+16). 6 accumulator banks (r,z,n x ih,hh).
__global__ __launch_bounds__(512, 1)
void gru_kernel(const float* __restrict__ agg,
                const float* __restrict__ nf,
                const float* __restrict__ W_ih, const float* __restrict__ b_ih,
                const float* __restrict__ W_hh, const float* __restrict__ b_hh,
                float* __restrict__ out)
{
    __shared__ float sa[TN][129];
    __shared__ float sh[TN][129];

    const int tid  = threadIdx.x;
    const int lane = tid & 63;                                  // node slot
    const int w    = __builtin_amdgcn_readfirstlane(tid >> 6);  // 0..7
    const int cb   = w * 16;
    const int n0   = blockIdx.x * TN;

    {   // stage agg + node_features rows: 8 threads per row
        const int r = tid >> 3, q = tid & 7;
        #pragma unroll
        for (int i = 0; i < 4; ++i) {
            int f4 = q + 8 * i;   // 32 float4 per row / 8 threads
            float4 va = *(const float4*)(agg + (size_t)(n0 + r) * ND + f4 * 4);
            sa[r][f4*4+0] = va.x; sa[r][f4*4+1] = va.y;
            sa[r][f4*4+2] = va.z; sa[r][f4*4+3] = va.w;
            float4 vh = *(const float4*)(nf + (size_t)(n0 + r) * ND + f4 * 4);
            sh[r][f4*4+0] = vh.x; sh[r][f4*4+1] = vh.y;
            sh[r][f4*4+2] = vh.z; sh[r][f4*4+3] = vh.w;
        }
    }
    __syncthreads();

    float ir[16], iz[16], inn[16], hr[16], hz[16], hn[16];
    #pragma unroll
    for (int j = 0; j < 16; ++j) {
        ir[j]  = b_ih[cb + j];
        iz[j]  = b_ih[128 + cb + j];
        inn[j] = b_ih[256 + cb + j];
        hr[j]  = b_hh[cb + j];
        hz[j]  = b_hh[128 + cb + j];
        hn[j]  = b_hh[256 + cb + j];
    }
    for (int k = 0; k < ND; ++k) {
        float xa = sa[lane][k];
        float xh = sh[lane][k];
        #pragma unroll
        for (int j = 0; j < 16; ++j) {
            ir[j]  = fmaf(xa, W_ih[(size_t)(cb + j) * ND + k],       ir[j]);
            iz[j]  = fmaf(xa, W_ih[(size_t)(128 + cb + j) * ND + k], iz[j]);
            inn[j] = fmaf(xa, W_ih[(size_t)(256 + cb + j) * ND + k], inn[j]);
            hr[j]  = fmaf(xh, W_hh[(size_t)(cb + j) * ND + k],       hr[j]);
            hz[j]  = fmaf(xh, W_hh[(size_t)(128 + cb + j) * ND + k], hz[j]);
            hn[j]  = fmaf(xh, W_hh[(size_t)(256 + cb + j) * ND + k], hn[j]);
        }
    }
    __syncthreads();   // done reading sa before overwrite
    #pragma unroll
    for (int j = 0; j < 16; ++j) {
        float rr  = sigmoidf_(ir[j] + hr[j]);
        float zz  = sigmoidf_(iz[j] + hz[j]);
        float nn  = tanhf(inn[j] + rr * hn[j]);
        float res = (1.f - zz) * nn + zz * sh[lane][cb + j];
        sa[lane][cb + j] = res;
    }
    __syncthreads();

    {   // coalesced store
        const int r = tid >> 3, q = tid & 7;
        #pragma unroll
        for (int i = 0; i < 4; ++i) {
            int f4 = q + 8 * i;
            float4 v;
            v.x = sa[r][f4*4+0]; v.y = sa[r][f4*4+1];
            v.z = sa[r][f4*4+2]; v.w = sa[r][f4*4+3];
            *(float4*)(out + (size_t)(n0 + r) * ND + f4 * 4) = v;
        }
    }
}

extern "C" void kernel_launch(void* const* d_in, const int* in_sizes, int n_in,
                              void* d_out, int out_size, void* d_ws, size_t ws_size,
                              hipStream_t stream) {
    const float* nf     = (const float*)d_in[0];
    const int*   eidx   = (const int*)  d_in[1];
    const float* ef     = (const float*)d_in[2];
    const float* W1     = (const float*)d_in[3];
    const float* b1     = (const float*)d_in[4];
    const float* ln_g   = (const float*)d_in[5];
    const float* ln_b   = (const float*)d_in[6];
    const float* W2     = (const float*)d_in[7];
    const float* b2     = (const float*)d_in[8];
    const float* gate_w = (const float*)d_in[9];
    const float* gate_b = (const float*)d_in[10];
    const float* W_ih   = (const float*)d_in[11];
    const float* b_ih   = (const float*)d_in[12];
    const float* W_hh   = (const float*)d_in[13];
    const float* b_hh   = (const float*)d_in[14];
    float* out = (float*)d_out;

    const int N = in_sizes[0] / ND;   // 40000
    const int E = in_sizes[1] / 2;    // 640000

    float* agg = (float*)d_ws;        // N x ND accumulator
    hipMemsetAsync(agg, 0, (size_t)N * ND * sizeof(float), stream);

    edge_kernel<<<E / TE, 256, 0, stream>>>(nf, eidx, ef, W1, b1, ln_g, ln_b,
                                            W2, b2, gate_w, gate_b, agg, E);
    gru_kernel<<<N / TN, 512, 0, stream>>>(agg, nf, W_ih, b_ih, W_hh, b_hh, out);
}

// Round 3
// 1360.285 us; speedup vs baseline: 1.5393x; 1.5393x over previous
//
#include <hip/hip_runtime.h>
#include <math.h>

#define ND 128
#define ED 64
#define LN_EPS 1e-5f
#define SXF 330   // edge LDS row stride (fp32): 330 dw ≡ 10 mod 32 -> conflict-free b128
#define GSF 132   // gru  LDS row stride (fp32): 132 dw ≡ 4 mod 32 -> 2-way (free)

typedef __attribute__((ext_vector_type(8))) short bf16x8;
typedef __attribute__((ext_vector_type(4))) float f32x4;

__device__ __forceinline__ unsigned short f2bf(float f) {
    union { float f; unsigned u; } v; v.f = f;
    unsigned r = v.u + 0x7FFFu + ((v.u >> 16) & 1u);   // RNE
    return (unsigned short)(r >> 16);
}
__device__ __forceinline__ float bf2f(unsigned short h) {
    union { unsigned u; float f; } v; v.u = ((unsigned)h) << 16;
    return v.f;
}
__device__ __forceinline__ float sigmoidf_(float x) { return 1.f / (1.f + expf(-x)); }

// split 8 consecutive fp32 (LDS) into hi/lo bf16 fragments
__device__ __forceinline__ void split8(const float* p, bf16x8& hi, bf16x8& lo) {
    float4 v0 = *(const float4*)p;
    float4 v1 = *(const float4*)(p + 4);
    float xv[8] = {v0.x, v0.y, v0.z, v0.w, v1.x, v1.y, v1.z, v1.w};
    #pragma unroll
    for (int j = 0; j < 8; ++j) {
        unsigned short h = f2bf(xv[j]);
        hi[j] = (short)h;
        lo[j] = (short)f2bf(xv[j] - bf2f(h));
    }
}

// ---- weight conversion: fp32 -> bf16 hi/lo pairs (+transpose for W1,W2) ----
__global__ void convert_kernel(const float* __restrict__ W1, const float* __restrict__ W2,
                               const float* __restrict__ Wih, const float* __restrict__ Whh,
                               unsigned short* __restrict__ W1h, unsigned short* __restrict__ W1l,
                               unsigned short* __restrict__ W2h, unsigned short* __restrict__ W2l,
                               unsigned short* __restrict__ Wihh, unsigned short* __restrict__ Wihl,
                               unsigned short* __restrict__ Whhh, unsigned short* __restrict__ Whhl)
{
    int idx = blockIdx.x * 256 + threadIdx.x;
    float v; unsigned short *ph, *pl; int o;
    if (idx < 40960)        { int n = idx / 320, k = idx - n * 320; v = W1[k * 128 + n]; ph = W1h; pl = W1l; o = idx; }
    else if (idx < 57344)   { int i2 = idx - 40960; int n = i2 >> 7, k = i2 & 127; v = W2[k * 128 + n]; ph = W2h; pl = W2l; o = i2; }
    else if (idx < 106496)  { int i3 = idx - 57344;  v = Wih[i3]; ph = Wihh; pl = Wihl; o = i3; }
    else                    { int i4 = idx - 106496; v = Whh[i4]; ph = Whhh; pl = Whhl; o = i4; }
    unsigned short h = f2bf(v);
    ph[o] = h;
    pl[o] = f2bf(v - bf2f(h));
}

// ---------------- edge message kernel (split-bf16 MFMA, fp32-accurate) ----------------
// 256 thr = 4 waves; 32 edges/block. Wave w: M-tile mt=w&1 (rows 16mt..16mt+16),
// N-half nh=w>>1 (cols 64nh..64nh+64). fp32 LDS tile; hi/lo split at fragment load.
__global__ __launch_bounds__(256, 3)
void edge_kernel(const float* __restrict__ nf, const int* __restrict__ eidx,
                 const float* __restrict__ ef,
                 const unsigned short* __restrict__ W1h, const unsigned short* __restrict__ W1l,
                 const float* __restrict__ b1,
                 const float* __restrict__ ln_g, const float* __restrict__ ln_b,
                 const unsigned short* __restrict__ W2h, const unsigned short* __restrict__ W2l,
                 const float* __restrict__ b2,
                 const float* __restrict__ gate_w, const float* __restrict__ gate_b,
                 float* __restrict__ agg, int E)
{
    __shared__ float sx[32 * SXF];          // 41.25 KB: x tile; cols[0,128) reused for h
    __shared__ float sred[2][2][16][2];     // LN partials [mt][nh][row][p1,p2]

    const int tid  = threadIdx.x;
    const int lane = tid & 63;
    const int w    = tid >> 6;
    const int mt   = w & 1, nh = w >> 1;
    const int c    = lane & 15;
    const int quad = lane >> 4;
    const int e0   = blockIdx.x * 32;

    // ---- stage 32 rows x 320 fp32: [nf[src] | nf[dst] | ef] ----
    {
        const int r = tid >> 3, q = tid & 7;
        const int srcI = eidx[e0 + r];
        const int dstI = eidx[E + e0 + r];
        const float* srow = nf + (size_t)srcI * ND;
        const float* drow = nf + (size_t)dstI * ND;
        const float* erow = ef + (size_t)(e0 + r) * ED;
        float* dp = sx + r * SXF;
        #pragma unroll
        for (int i = 0; i < 10; ++i) {
            int f4 = q + 8 * i;
            const float* s = (f4 < 32) ? (srow + f4 * 4)
                           : (f4 < 64) ? (drow + (f4 - 32) * 4)
                                       : (erow + (f4 - 64) * 4);
            *(float4*)(dp + f4 * 4) = *(const float4*)s;
        }
    }
    __syncthreads();

    const int myrow = 16 * mt + c;

    // ---- edge gate (fp32, quad-split + shuffle reduce) ----
    float g;
    {
        float gp = 0.f;
        const float* er = sx + myrow * SXF + 256 + quad * 16;
        #pragma unroll
        for (int k = 0; k < 16; ++k) gp = fmaf(er[k], gate_w[quad * 16 + k], gp);
        gp += __shfl_xor(gp, 16);
        gp += __shfl_xor(gp, 32);
        g = sigmoidf_(gp + gate_b[0]);
    }

    // ---- GEMM1: [16x320]@[320x128], 3-term split ----
    f32x4 acc[4];
    #pragma unroll
    for (int t = 0; t < 4; ++t) acc[t] = (f32x4){0.f, 0.f, 0.f, 0.f};
    #pragma unroll
    for (int ks = 0; ks < 10; ++ks) {
        bf16x8 ahi, alo;
        split8(sx + myrow * SXF + ks * 32 + quad * 8, ahi, alo);
        #pragma unroll
        for (int ntl = 0; ntl < 4; ++ntl) {
            int col = (4 * nh + ntl) * 16 + c;
            bf16x8 bh = *(const bf16x8*)(W1h + col * 320 + ks * 32 + quad * 8);
            bf16x8 bl = *(const bf16x8*)(W1l + col * 320 + ks * 32 + quad * 8);
            acc[ntl] = __builtin_amdgcn_mfma_f32_16x16x32_bf16(ahi, bh, acc[ntl], 0, 0, 0);
            acc[ntl] = __builtin_amdgcn_mfma_f32_16x16x32_bf16(alo, bh, acc[ntl], 0, 0, 0);
            acc[ntl] = __builtin_amdgcn_mfma_f32_16x16x32_bf16(ahi, bl, acc[ntl], 0, 0, 0);
        }
    }

    // ---- bias + LayerNorm (cross-wave pair exchange) + ReLU, h -> LDS fp32 ----
    float b1v[4], gv[4], bv[4];
    #pragma unroll
    for (int ntl = 0; ntl < 4; ++ntl) {
        int col = (4 * nh + ntl) * 16 + c;
        b1v[ntl] = b1[col]; gv[ntl] = ln_g[col]; bv[ntl] = ln_b[col];
    }
    float p1[4] = {0, 0, 0, 0}, p2[4] = {0, 0, 0, 0};
    #pragma unroll
    for (int ntl = 0; ntl < 4; ++ntl)
        #pragma unroll
        for (int r = 0; r < 4; ++r) {
            float vv = acc[ntl][r] + b1v[ntl];
            acc[ntl][r] = vv;
            p1[r] += vv; p2[r] += vv * vv;
        }
    #pragma unroll
    for (int m = 1; m < 16; m <<= 1)
        #pragma unroll
        for (int r = 0; r < 4; ++r) {
            p1[r] += __shfl_xor(p1[r], m);
            p2[r] += __shfl_xor(p2[r], m);
        }
    if (c == 0) {
        #pragma unroll
        for (int r = 0; r < 4; ++r) {
            sred[mt][nh][quad * 4 + r][0] = p1[r];
            sred[mt][nh][quad * 4 + r][1] = p2[r];
        }
    }
    __syncthreads();
    float mu[4], rs[4];
    #pragma unroll
    for (int r = 0; r < 4; ++r) {
        int row = quad * 4 + r;
        float t1 = sred[mt][0][row][0] + sred[mt][1][row][0];
        float t2 = sred[mt][0][row][1] + sred[mt][1][row][1];
        mu[r] = t1 * (1.f / 128.f);
        float var = t2 * (1.f / 128.f) - mu[r] * mu[r];
        rs[r] = rsqrtf(var + LN_EPS);
    }
    #pragma unroll
    for (int ntl = 0; ntl < 4; ++ntl)
        #pragma unroll
        for (int r = 0; r < 4; ++r) {
            float vv = (acc[ntl][r] - mu[r]) * rs[r] * gv[ntl] + bv[ntl];
            vv = vv > 0.f ? vv : 0.f;
            sx[(16 * mt + quad * 4 + r) * SXF + (4 * nh + ntl) * 16 + c] = vv;
        }
    __syncthreads();

    // ---- GEMM2: [16x128]@[128x128], 3-term split ----
    f32x4 acc2[4];
    #pragma unroll
    for (int t = 0; t < 4; ++t) acc2[t] = (f32x4){0.f, 0.f, 0.f, 0.f};
    #pragma unroll
    for (int ks = 0; ks < 4; ++ks) {
        bf16x8 ahi, alo;
        split8(sx + myrow * SXF + ks * 32 + quad * 8, ahi, alo);
        #pragma unroll
        for (int ntl = 0; ntl < 4; ++ntl) {
            int col = (4 * nh + ntl) * 16 + c;
            bf16x8 bh = *(const bf16x8*)(W2h + col * 128 + ks * 32 + quad * 8);
            bf16x8 bl = *(const bf16x8*)(W2l + col * 128 + ks * 32 + quad * 8);
            acc2[ntl] = __builtin_amdgcn_mfma_f32_16x16x32_bf16(ahi, bh, acc2[ntl], 0, 0, 0);
            acc2[ntl] = __builtin_amdgcn_mfma_f32_16x16x32_bf16(alo, bh, acc2[ntl], 0, 0, 0);
            acc2[ntl] = __builtin_amdgcn_mfma_f32_16x16x32_bf16(ahi, bl, acc2[ntl], 0, 0, 0);
        }
    }

    // ---- gate + scatter-add ----
    float g4[4]; int d4[4];
    #pragma unroll
    for (int r = 0; r < 4; ++r) {
        g4[r] = __shfl(g, quad * 4 + r);
        d4[r] = eidx[E + e0 + 16 * mt + quad * 4 + r];
    }
    #pragma unroll
    for (int ntl = 0; ntl < 4; ++ntl) {
        int col = (4 * nh + ntl) * 16 + c;
        float b2v = b2[col];
        #pragma unroll
        for (int r = 0; r < 4; ++r) {
            float vv = (acc2[ntl][r] + b2v) * g4[r];
            atomicAdd(agg + (size_t)d4[r] * ND + col, vv);
        }
    }
}

// ---------------- GRU kernel (split-bf16 MFMA) ----------------
// 256 thr = 4 waves; 32 nodes/block. Wave w owns gate-cols [32w,32w+32).
__global__ __launch_bounds__(256, 2)
void gru_kernel(const float* __restrict__ agg, const float* __restrict__ nf,
                const unsigned short* __restrict__ Wihh, const unsigned short* __restrict__ Wihl,
                const float* __restrict__ b_ih,
                const unsigned short* __restrict__ Whhh, const unsigned short* __restrict__ Whhl,
                const float* __restrict__ b_hh,
                float* __restrict__ out)
{
    __shared__ float sa[32 * GSF];
    __shared__ float sh[32 * GSF];

    const int tid  = threadIdx.x;
    const int lane = tid & 63;
    const int w    = tid >> 6;
    const int c    = lane & 15;
    const int quad = lane >> 4;
    const int n0   = blockIdx.x * 32;

    {
        const int r = tid >> 3, q = tid & 7;
        const float* arow = agg + (size_t)(n0 + r) * ND;
        const float* hrow = nf  + (size_t)(n0 + r) * ND;
        #pragma unroll
        for (int i = 0; i < 4; ++i) {
            int f4 = q + 8 * i;
            *(float4*)(sa + r * GSF + f4 * 4) = *(const float4*)(arow + f4 * 4);
            *(float4*)(sh + r * GSF + f4 * 4) = *(const float4*)(hrow + f4 * 4);
        }
    }
    __syncthreads();

    f32x4 aI[2][6], aH[2][6];   // [mt][gg*2+nt]
    #pragma unroll
    for (int mt = 0; mt < 2; ++mt)
        #pragma unroll
        for (int j = 0; j < 6; ++j) {
            aI[mt][j] = (f32x4){0.f, 0.f, 0.f, 0.f};
            aH[mt][j] = (f32x4){0.f, 0.f, 0.f, 0.f};
        }

    #pragma unroll
    for (int ks = 0; ks < 4; ++ks) {
        bf16x8 fah[2], fal[2], fhh[2], fhl[2];
        #pragma unroll
        for (int mt = 0; mt < 2; ++mt) {
            split8(sa + (mt * 16 + c) * GSF + ks * 32 + quad * 8, fah[mt], fal[mt]);
            split8(sh + (mt * 16 + c) * GSF + ks * 32 + quad * 8, fhh[mt], fhl[mt]);
        }
        #pragma unroll
        for (int gg = 0; gg < 3; ++gg)
            #pragma unroll
            for (int nt = 0; nt < 2; ++nt) {
                int coln = gg * 128 + 32 * w + nt * 16 + c;
                bf16x8 bIh = *(const bf16x8*)(Wihh + coln * 128 + ks * 32 + quad * 8);
                bf16x8 bIl = *(const bf16x8*)(Wihl + coln * 128 + ks * 32 + quad * 8);
                bf16x8 bHh = *(const bf16x8*)(Whhh + coln * 128 + ks * 32 + quad * 8);
                bf16x8 bHl = *(const bf16x8*)(Whhl + coln * 128 + ks * 32 + quad * 8);
                #pragma unroll
                for (int mt = 0; mt < 2; ++mt) {
                    int j = gg * 2 + nt;
                    aI[mt][j] = __builtin_amdgcn_mfma_f32_16x16x32_bf16(fah[mt], bIh, aI[mt][j], 0, 0, 0);
                    aI[mt][j] = __builtin_amdgcn_mfma_f32_16x16x32_bf16(fal[mt], bIh, aI[mt][j], 0, 0, 0);
                    aI[mt][j] = __builtin_amdgcn_mfma_f32_16x16x32_bf16(fah[mt], bIl, aI[mt][j], 0, 0, 0);
                    aH[mt][j] = __builtin_amdgcn_mfma_f32_16x16x32_bf16(fhh[mt], bHh, aH[mt][j], 0, 0, 0);
                    aH[mt][j] = __builtin_amdgcn_mfma_f32_16x16x32_bf16(fhl[mt], bHh, aH[mt][j], 0, 0, 0);
                    aH[mt][j] = __builtin_amdgcn_mfma_f32_16x16x32_bf16(fhh[mt], bHl, aH[mt][j], 0, 0, 0);
                }
            }
    }

    #pragma unroll
    for (int nt = 0; nt < 2; ++nt) {
        int col = 32 * w + nt * 16 + c;
        float bir = b_ih[col], biz = b_ih[128 + col], bin = b_ih[256 + col];
        float bhr = b_hh[col], bhz = b_hh[128 + col], bhn = b_hh[256 + col];
        #pragma unroll
        for (int mt = 0; mt < 2; ++mt)
            #pragma unroll
            for (int r = 0; r < 4; ++r) {
                int row = mt * 16 + quad * 4 + r;
                float rr = sigmoidf_(aI[mt][0 + nt][r] + bir + aH[mt][0 + nt][r] + bhr);
                float zz = sigmoidf_(aI[mt][2 + nt][r] + biz + aH[mt][2 + nt][r] + bhz);
                float nn = tanhf(aI[mt][4 + nt][r] + bin + rr * (aH[mt][4 + nt][r] + bhn));
                float hp = sh[row * GSF + col];
                out[(size_t)(n0 + row) * ND + col] = (1.f - zz) * nn + zz * hp;
            }
    }
}

extern "C" void kernel_launch(void* const* d_in, const int* in_sizes, int n_in,
                              void* d_out, int out_size, void* d_ws, size_t ws_size,
                              hipStream_t stream) {
    const float* nf     = (const float*)d_in[0];
    const int*   eidx   = (const int*)  d_in[1];
    const float* ef     = (const float*)d_in[2];
    const float* W1     = (const float*)d_in[3];
    const float* b1     = (const float*)d_in[4];
    const float* ln_g   = (const float*)d_in[5];
    const float* ln_b   = (const float*)d_in[6];
    const float* W2     = (const float*)d_in[7];
    const float* b2     = (const float*)d_in[8];
    const float* gate_w = (const float*)d_in[9];
    const float* gate_b = (const float*)d_in[10];
    const float* W_ih   = (const float*)d_in[11];
    const float* b_ih   = (const float*)d_in[12];
    const float* W_hh   = (const float*)d_in[13];
    const float* b_hh   = (const float*)d_in[14];
    float* out = (float*)d_out;

    const int N = in_sizes[0] / ND;   // 40000
    const int E = in_sizes[1] / 2;    // 640000

    char* ws = (char*)d_ws;
    float* agg = (float*)ws;                      ws += (size_t)N * ND * 4;   // 20.48 MB (16B-aligned)
    unsigned short* W1h  = (unsigned short*)ws;   ws += 40960 * 2;
    unsigned short* W1l  = (unsigned short*)ws;   ws += 40960 * 2;
    unsigned short* W2h  = (unsigned short*)ws;   ws += 16384 * 2;
    unsigned short* W2l  = (unsigned short*)ws;   ws += 16384 * 2;
    unsigned short* Wihh = (unsigned short*)ws;   ws += 49152 * 2;
    unsigned short* Wihl = (unsigned short*)ws;   ws += 49152 * 2;
    unsigned short* Whhh = (unsigned short*)ws;   ws += 49152 * 2;
    unsigned short* Whhl = (unsigned short*)ws;   ws += 49152 * 2;

    hipMemsetAsync(agg, 0, (size_t)N * ND * 4, stream);
    convert_kernel<<<608, 256, 0, stream>>>(W1, W2, W_ih, W_hh,
                                            W1h, W1l, W2h, W2l, Wihh, Wihl, Whhh, Whhl);
    edge_kernel<<<E / 32, 256, 0, stream>>>(nf, eidx, ef, W1h, W1l, b1, ln_g, ln_b,
                                            W2h, W2l, b2, gate_w, gate_b, agg, E);
    gru_kernel<<<N / 32, 256, 0, stream>>>(agg, nf, Wihh, Wihl, b_ih, Whhh, Whhl, b_hh, out);
}